// Round 1
// 337.453 us; speedup vs baseline: 1.0716x; 1.0716x over previous
//
#include <hip/hip_runtime.h>
#include <cstddef>
#include <cstdint>

#define VOCAB 32000
#define EMB 32
#define HID 64
#define NG 256      // 4*HID
#define BATCH 1024
#define SEQ 512
#define NB 4        // real batch rows per block, mapped to M-rows 0,4,8,12
#define ROWB 72     // halfs per H row: 64 + 8 pad (row stride 144 B)
#define PFD 8       // xg gather prefetch depth (steps ahead)

typedef short short8 __attribute__((ext_vector_type(8)));
typedef _Float16 half8 __attribute__((ext_vector_type(8)));
typedef float floatx4 __attribute__((ext_vector_type(4)));
typedef int int4v __attribute__((ext_vector_type(4)));

union FragH {
  half8 h;
  int4v v;
};

__device__ __forceinline__ float fast_sig(float x) {
  return __builtin_amdgcn_rcpf(1.0f + __expf(-x));
}
__device__ __forceinline__ float fast_tanh(float x) {
  // 1 - 2/(e^{2x}+1); saturates correctly at +-inf via rcp(inf)=0
  return fmaf(-2.0f, __builtin_amdgcn_rcpf(__expf(2.0f * x) + 1.0f), 1.0f);
}

// ---------------- Kernel 1: fused embedding+input-proj table ----------------
// GATE-INTERLEAVED layout: table[v*256 + h*4 + g], g in {i,f,g,o}.
// Thread tid computes gate row gidx = (tid&3)*64 + (tid>>2) so that the WRITE
// at column `tid` stays perfectly coalesced while the layout permutes.
#define K1_ROWS 32
__global__ __launch_bounds__(256) void build_table(
    const float* __restrict__ emb, const float* __restrict__ W_ih,
    const float* __restrict__ b_ih, const float* __restrict__ b_hh,
    float* __restrict__ table) {
  __shared__ __align__(16) float erow[K1_ROWS * EMB];
  const int tid = threadIdx.x;
  const int v0 = blockIdx.x * K1_ROWS;
  const int gidx = (tid & 3) * 64 + (tid >> 2);  // W_ih row this thread owns

  float w[EMB];
#pragma unroll
  for (int e = 0; e < EMB; e += 4) {
    const float4 t = *(const float4*)&W_ih[gidx * EMB + e];
    w[e] = t.x; w[e + 1] = t.y; w[e + 2] = t.z; w[e + 3] = t.w;
  }
  const float bsum = b_ih[gidx] + b_hh[gidx];

  ((float4*)erow)[tid] = ((const float4*)&emb[(size_t)v0 * EMB])[tid];
  __syncthreads();

#pragma unroll 4
  for (int r = 0; r < K1_ROWS; ++r) {
    float acc = bsum;
#pragma unroll
    for (int e = 0; e < EMB; ++e) acc += erow[r * EMB + e] * w[e];
    table[(size_t)(v0 + r) * NG + tid] = acc;  // coalesced; layout is h*4+g
  }
}

// ---------------- Kernel 2: LSTM recurrence via MFMA (fp16 single-product) --
// Grid: BATCH/NB = 256 blocks x 256 threads (4 waves), 1 block/CU.
// Each lane owns exactly one (batch=blk*4+quad, hid=w*16+col) state.
// Changes vs previous version:
//  - xg gather is ONE dwordx4/lane/step (gate-interleaved table)
//  - prefetch depth 8 (named float4 sets, loop unrolled x8)
//  - xg added AFTER the MFMAs (acc zero-initialized per step) so the vmcnt
//    consume point sits past the ds_read+MFMA chain.
__global__ __launch_bounds__(256) void lstm_mfma(
    const int* __restrict__ x, const float* __restrict__ table,
    const float* __restrict__ W_hh, float* __restrict__ h_out) {
  __shared__ __align__(16) _Float16 Hs[2][16 * ROWB];  // [buf][row][hid]
  __shared__ int xls[NB * SEQ];

  const int tid = threadIdx.x;
  const int w = tid >> 6;       // wave 0..3
  const int lane = tid & 63;
  const int quad = lane >> 4;   // 0..3 -> owns batch row blk*4+quad (M-row 4*quad)
  const int col = lane & 15;    // MFMA n-col / A m-row
  const int blk = blockIdx.x;
  const int myhid = w * 16 + col;

  // zero H buffers (junk rows read as A must be exactly zero)
  {
    int* hz = (int*)&Hs[0][0];
    const int nz = (int)(sizeof(Hs) / 4);
    for (int i = tid; i < nz; i += 256) hz[i] = 0;
  }
  // stage this block's token ids
  {
    const int* xsrc = &x[(size_t)blk * NB * SEQ];
    for (int i = tid; i < NB * SEQ; i += 256) xls[i] = xsrc[i];
  }

  // resident W_hh fragments (fp16): B[k][n], n = (w+ti*4)*16+col, k = ko*32+quad*8+j
  FragH Bf[4][2];
#pragma unroll
  for (int ti = 0; ti < 4; ++ti) {
    const int n = (w + ti * 4) * 16 + col;
#pragma unroll
    for (int ko = 0; ko < 2; ++ko) {
      const float* src = &W_hh[n * HID + ko * 32 + quad * 8];
#pragma unroll
      for (int j = 0; j < 8; ++j) Bf[ti][ko].h[j] = (_Float16)src[j];
    }
  }

  float c = 0.0f, hcur = 0.0f;

  __syncthreads();  // xls/Hs visible

  const int xrow = quad * SEQ;
  const float* __restrict__ tb4 = table + (size_t)myhid * 4;

  auto gather = [&](int tt) -> float4 {
    return *(const float4*)(tb4 + ((size_t)(unsigned)xls[xrow + tt] << 8));
  };

  // prologue: fill the 8-deep prefetch pipeline
  float4 xg0 = gather(0), xg1 = gather(1), xg2 = gather(2), xg3 = gather(3);
  float4 xg4 = gather(4), xg5 = gather(5), xg6 = gather(6), xg7 = gather(7);

  auto step = [&](float4& XG, const int RB, const int TT) {
    // consume the PFD-step-old gather into temps (vmcnt wait ~0 here),
    // then immediately re-issue this set for step TT+PFD
    const float xi = XG.x, xf = XG.y, xgg = XG.z, xo = XG.w;
    {
      const int tn = (TT + PFD < SEQ) ? TT + PFD : SEQ - 1;
      XG = gather(tn);
    }

    // A fragments: A[m=col][k = ko*32 + quad*8 + j]
    const int abase = col * ROWB + quad * 8;
    FragH A0, A1;
    A0.v = *(const int4v*)&Hs[RB][abase];
    A1.v = *(const int4v*)&Hs[RB][abase + 32];

    floatx4 g4[4];
#pragma unroll
    for (int ti = 0; ti < 4; ++ti) {
      floatx4 a = (floatx4){0.f, 0.f, 0.f, 0.f};
      a = __builtin_amdgcn_mfma_f32_16x16x32_f16(A0.h, Bf[ti][0].h, a, 0, 0, 0);
      a = __builtin_amdgcn_mfma_f32_16x16x32_f16(A1.h, Bf[ti][1].h, a, 0, 0, 0);
      g4[ti] = a;
    }

    // one real state per lane: (batch=blk*4+quad, hid=myhid) at acc reg 0
    {
      const float gi = fast_sig(g4[0][0] + xi);
      const float gf = fast_sig(g4[1][0] + xf);
      const float gg = fast_tanh(g4[2][0] + xgg);
      const float go = fast_sig(g4[3][0] + xo);
      c = gf * c + gi * gg;
      hcur = go * fast_tanh(c);
      Hs[RB ^ 1][(quad * 4) * ROWB + myhid] = (_Float16)hcur;  // M-row 4*quad
    }
    __syncthreads();
  };

  for (int t = 0; t < SEQ; t += 8) {
    step(xg0, 0, t);
    step(xg1, 1, t + 1);
    step(xg2, 0, t + 2);
    step(xg3, 1, t + 3);
    step(xg4, 0, t + 4);
    step(xg5, 1, t + 5);
    step(xg6, 0, t + 6);
    step(xg7, 1, t + 7);
  }

  h_out[((size_t)blk * NB + quad) * HID + myhid] = hcur;
}

// ---------------- Kernel 3: FC to vocab ----------------
#define FC_BB 128
#define FC_BV 128
#define FC_PAD 4
__global__ __launch_bounds__(256) void fc_kernel(
    const float* __restrict__ h, const float* __restrict__ fc_W,
    const float* __restrict__ fc_b, float* __restrict__ out) {
  __shared__ __align__(16) float sh[HID][FC_BB + FC_PAD];
  __shared__ __align__(16) float sw[HID][FC_BV + FC_PAD];
  const int tid = threadIdx.x;
  const int v0 = blockIdx.x * FC_BV;
  const int b0 = blockIdx.y * FC_BB;
  const int ti = tid >> 4;
  const int tj = tid & 15;

  const float4 bias0 = *(const float4*)&fc_b[v0 + tj * 4];
  const float4 bias1 = *(const float4*)&fc_b[v0 + 64 + tj * 4];

  {
    const float4* src = (const float4*)&h[(size_t)b0 * HID];
#pragma unroll
    for (int i = 0; i < 8; ++i) {
      const int idx = tid + i * 256;
      const float4 t = src[idx];
      const int bl = idx >> 4;
      const int k = (idx * 4) & (HID - 1);
      sh[k][bl] = t.x; sh[k + 1][bl] = t.y; sh[k + 2][bl] = t.z; sh[k + 3][bl] = t.w;
    }
    const float4* wsrc = (const float4*)&fc_W[(size_t)v0 * HID];
#pragma unroll
    for (int i = 0; i < 8; ++i) {
      const int idx = tid + i * 256;
      const float4 t = wsrc[idx];
      const int vl = idx >> 4;
      const int k = (idx * 4) & (HID - 1);
      sw[k][vl] = t.x; sw[k + 1][vl] = t.y; sw[k + 2][vl] = t.z; sw[k + 3][vl] = t.w;
    }
  }
  __syncthreads();

  float acc[8][8];
#pragma unroll
  for (int i = 0; i < 8; ++i)
#pragma unroll
    for (int j = 0; j < 8; ++j) acc[i][j] = 0.0f;

#pragma unroll 4
  for (int k = 0; k < HID; ++k) {
    const float4 h0 = *(const float4*)&sh[k][ti * 8];
    const float4 h1 = *(const float4*)&sh[k][ti * 8 + 4];
    const float4 w0 = *(const float4*)&sw[k][tj * 4];
    const float4 w1 = *(const float4*)&sw[k][64 + tj * 4];
    const float hv[8] = {h0.x, h0.y, h0.z, h0.w, h1.x, h1.y, h1.z, h1.w};
    const float wv[8] = {w0.x, w0.y, w0.z, w0.w, w1.x, w1.y, w1.z, w1.w};
#pragma unroll
    for (int i = 0; i < 8; ++i)
#pragma unroll
      for (int j = 0; j < 8; ++j) acc[i][j] += hv[i] * wv[j];
  }

#pragma unroll
  for (int i = 0; i < 8; ++i) {
    const size_t row = (size_t)(b0 + ti * 8 + i) * VOCAB;
    float4 o0, o1;
    o0.x = acc[i][0] + bias0.x; o0.y = acc[i][1] + bias0.y;
    o0.z = acc[i][2] + bias0.z; o0.w = acc[i][3] + bias0.w;
    o1.x = acc[i][4] + bias1.x; o1.y = acc[i][5] + bias1.y;
    o1.z = acc[i][6] + bias1.z; o1.w = acc[i][7] + bias1.w;
    *(float4*)&out[row + v0 + tj * 4] = o0;
    *(float4*)&out[row + v0 + 64 + tj * 4] = o1;
  }
}

extern "C" void kernel_launch(void* const* d_in, const int* in_sizes, int n_in,
                              void* d_out, int out_size, void* d_ws, size_t ws_size,
                              hipStream_t stream) {
  const int* x = (const int*)d_in[0];
  const float* emb = (const float*)d_in[1];
  const float* W_ih = (const float*)d_in[2];
  const float* W_hh = (const float*)d_in[3];
  const float* b_ih = (const float*)d_in[4];
  const float* b_hh = (const float*)d_in[5];
  const float* fc_W = (const float*)d_in[6];
  const float* fc_b = (const float*)d_in[7];
  float* out = (float*)d_out;

  // table (32.77 MB) lives in d_out: read only by lstm_mfma, which completes
  // (stream-ordered) before fc_kernel overwrites d_out. h_last in d_ws.
  float* table = out;
  float* hbuf = (float*)d_ws;

  build_table<<<VOCAB / K1_ROWS, 256, 0, stream>>>(emb, W_ih, b_ih, b_hh, table);
  lstm_mfma<<<BATCH / NB, 256, 0, stream>>>(x, table, W_hh, hbuf);
  dim3 g3(VOCAB / FC_BV, BATCH / FC_BB);
  fc_kernel<<<g3, 256, 0, stream>>>(hbuf, fc_W, fc_b, out);
}